// Round 1
// baseline (248.905 us; speedup 1.0000x reference)
//
#include <hip/hip_runtime.h>

// EdgeModel: out = leaky_relu(concat(x_s[src], x_t[tgt], edge_attr, u[batch]) @ W1 + b1) @ W2 + b2
// F_XS=10, F_XT=5, F_E=10, F_U=10  -> concat dim 35, hidden 10, out 10.
// One thread per edge; weights are wave-uniform -> compiler emits s_load (scalar cache).

#define F_XS 10
#define F_XT 5
#define F_E  10
#define F_U  10
#define F_IN 35

__global__ __launch_bounds__(256) void edge_model_kernel(
    const float* __restrict__ x_s,        // [N_S, 10]
    const float* __restrict__ x_t,        // [N_T, 5]
    const int*   __restrict__ edge_index, // [2, E]
    const float* __restrict__ edge_attr,  // [E, 10]
    const float* __restrict__ u,          // [B, 10]
    const int*   __restrict__ batch_e,    // [E]
    const float* __restrict__ W1,         // [35, 10]
    const float* __restrict__ b1,         // [10]
    const float* __restrict__ W2,         // [10, 10]
    const float* __restrict__ b2,         // [10]
    float*       __restrict__ out,        // [E, 10]
    int E)
{
    const int e = blockIdx.x * blockDim.x + threadIdx.x;
    if (e >= E) return;

    const int src = edge_index[e];
    const int tgt = edge_index[E + e];
    const int be  = batch_e[e];

    float in[F_IN];

    // x_s[src]: 40 B row, 8-aligned -> float2 gather
    {
        const float2* p = (const float2*)(x_s + (long long)src * F_XS);
        #pragma unroll
        for (int i = 0; i < 5; ++i) { float2 v = p[i]; in[2*i] = v.x; in[2*i+1] = v.y; }
    }
    // x_t[tgt]: 20 B row, only 4-aligned -> scalar gather
    {
        const float* p = x_t + (long long)tgt * F_XT;
        #pragma unroll
        for (int i = 0; i < 5; ++i) in[10 + i] = p[i];
    }
    // edge_attr[e]: streaming, coalesced float2
    {
        const float2* p = (const float2*)(edge_attr + (long long)e * F_E);
        #pragma unroll
        for (int i = 0; i < 5; ++i) { float2 v = p[i]; in[15 + 2*i] = v.x; in[16 + 2*i] = v.y; }
    }
    // u[batch_e[e]]: 40 B row, 8-aligned -> float2 gather (L2-resident, 0.4 MB table)
    {
        const float2* p = (const float2*)(u + (long long)be * F_U);
        #pragma unroll
        for (int i = 0; i < 5; ++i) { float2 v = p[i]; in[25 + 2*i] = v.x; in[26 + 2*i] = v.y; }
    }

    // Layer 1: h = leaky_relu(in @ W1 + b1), W1 accessed uniformly -> s_load
    float h[F_E];
    #pragma unroll
    for (int j = 0; j < F_E; ++j) h[j] = b1[j];
    #pragma unroll
    for (int k = 0; k < F_IN; ++k) {
        const float a = in[k];
        #pragma unroll
        for (int j = 0; j < F_E; ++j) h[j] = fmaf(a, W1[k * F_E + j], h[j]);
    }
    #pragma unroll
    for (int j = 0; j < F_E; ++j) h[j] = (h[j] >= 0.0f) ? h[j] : 0.1f * h[j];

    // Layer 2: o = h @ W2 + b2
    float o[F_E];
    #pragma unroll
    for (int j = 0; j < F_E; ++j) o[j] = b2[j];
    #pragma unroll
    for (int k = 0; k < F_E; ++k) {
        const float a = h[k];
        #pragma unroll
        for (int j = 0; j < F_E; ++j) o[j] = fmaf(a, W2[k * F_E + j], o[j]);
    }

    // Store: 40 B row, 8-aligned, coalesced float2
    float2* po = (float2*)(out + (long long)e * F_E);
    #pragma unroll
    for (int i = 0; i < 5; ++i) {
        float2 v; v.x = o[2*i]; v.y = o[2*i + 1];
        po[i] = v;
    }
}

extern "C" void kernel_launch(void* const* d_in, const int* in_sizes, int n_in,
                              void* d_out, int out_size, void* d_ws, size_t ws_size,
                              hipStream_t stream) {
    const float* x_s        = (const float*)d_in[0];
    const float* x_t        = (const float*)d_in[1];
    const int*   edge_index = (const int*)  d_in[2];
    const float* edge_attr  = (const float*)d_in[3];
    const float* u          = (const float*)d_in[4];
    const int*   batch_e    = (const int*)  d_in[5];
    const float* W1         = (const float*)d_in[6];
    const float* b1         = (const float*)d_in[7];
    const float* W2         = (const float*)d_in[8];
    const float* b2         = (const float*)d_in[9];
    float*       out        = (float*)d_out;

    const int E = in_sizes[5];  // batch_e is [E]
    const int block = 256;
    const int grid  = (E + block - 1) / block;

    edge_model_kernel<<<grid, block, 0, stream>>>(
        x_s, x_t, edge_index, edge_attr, u, batch_e, W1, b1, W2, b2, out, E);
}